// Round 1
// baseline (1237.593 us; speedup 1.0000x reference)
//
#include <hip/hip_runtime.h>
#include <hip/hip_bf16.h>
#include <math.h>

#define N_NODES 100000
#define G_GRAPHS 8

// ---------- helpers ----------
__device__ __forceinline__ unsigned fmap(float f) {
    unsigned b = __float_as_uint(f);
    return (b & 0x80000000u) ? ~b : (b | 0x80000000u);
}
__device__ __forceinline__ float funmap(unsigned u) {
    unsigned b = (u & 0x80000000u) ? (u & 0x7fffffffu) : ~u;
    return __uint_as_float(b);
}

// ---------- CSR build ----------
__global__ void k_count(const int* __restrict__ dst, int* __restrict__ deg, int E) {
    int e = blockIdx.x * 256 + threadIdx.x;
    if (e < E) atomicAdd(&deg[dst[e]], 1);
}

__global__ void k_dis(const int* __restrict__ deg, float* __restrict__ dis, int N) {
    int i = blockIdx.x * 256 + threadIdx.x;
    if (i < N) dis[i] = rsqrtf((float)(deg[i] + 1));  // +1 = self loop
}

__global__ void k_scanA(const int* __restrict__ deg, int* __restrict__ rowst,
                        int* __restrict__ bsum, int N) {
    __shared__ int s[256];
    int i = blockIdx.x * 256 + threadIdx.x;
    int v = (i < N) ? deg[i] : 0;
    s[threadIdx.x] = v;
    __syncthreads();
    for (int off = 1; off < 256; off <<= 1) {
        int t = (threadIdx.x >= off) ? s[threadIdx.x - off] : 0;
        __syncthreads();
        s[threadIdx.x] += t;
        __syncthreads();
    }
    if (i < N) rowst[i] = s[threadIdx.x] - v;   // block-local exclusive
    if (threadIdx.x == 255) bsum[blockIdx.x] = s[255];
}

__global__ void k_scanB(int* __restrict__ bsum, int NB) {
    __shared__ int s[512];
    int t = threadIdx.x;
    int v = (t < NB) ? bsum[t] : 0;
    s[t] = v;
    __syncthreads();
    for (int off = 1; off < 512; off <<= 1) {
        int x = (t >= off) ? s[t - off] : 0;
        __syncthreads();
        s[t] += x;
        __syncthreads();
    }
    if (t < NB) bsum[t] = s[t] - v;             // exclusive
}

__global__ void k_scanC(int* __restrict__ rowst, const int* __restrict__ bsum, int N) {
    int i = blockIdx.x * 256 + threadIdx.x;
    if (i < N) rowst[i] += bsum[blockIdx.x];
}

__global__ void k_fill(const int* __restrict__ src, const int* __restrict__ dst,
                       const float* __restrict__ dis, const int* __restrict__ rowst,
                       int* __restrict__ cnt, int* __restrict__ col,
                       float* __restrict__ wgt, int E) {
    int e = blockIdx.x * 256 + threadIdx.x;
    if (e >= E) return;
    int d = dst[e], s = src[e];
    int p = rowst[d] + atomicAdd(&cnt[d], 1);
    col[p] = s;
    wgt[p] = dis[s] * dis[d];
}

// ---------- propagation ----------
// dim-16 prop of raw x (prop(x) before @W1, since prop is linear)
__global__ void k_prop16(const float* __restrict__ x, float* __restrict__ out,
                         const float* __restrict__ dis, const int* __restrict__ rowst,
                         const int* __restrict__ deg, const int* __restrict__ col,
                         const float* __restrict__ wgt, int N) {
    int f = threadIdx.x & 15, g = threadIdx.x >> 4;
    int node = blockIdx.x * 16 + g;
    if (node >= N) return;
    float d = dis[node];
    float acc = x[node * 16 + f] * d * d;      // self loop
    int s = rowst[node], e = s + deg[node];
    for (int i = s; i < e; ++i)
        acc += wgt[i] * x[col[i] * 16 + f];
    out[node * 16 + f] = acc;
}

// dim-64 prop; wave per node, lane = feature
__global__ void k_prop64(const float* __restrict__ in, float* __restrict__ out,
                         const float* __restrict__ dis, const int* __restrict__ rowst,
                         const int* __restrict__ deg, const int* __restrict__ col,
                         const float* __restrict__ wgt,
                         const float* __restrict__ bias, int relu, int N) {
    int f = threadIdx.x & 63, w = threadIdx.x >> 6;
    int node = blockIdx.x * 4 + w;
    if (node >= N) return;
    float d = dis[node];
    float acc = in[node * 64 + f] * d * d;
    int s = rowst[node], e = s + deg[node];
    int i = s;
    for (; i + 1 < e; i += 2) {
        int c0 = col[i], c1 = col[i + 1];
        float w0 = wgt[i], w1 = wgt[i + 1];
        acc += w0 * in[c0 * 64 + f];
        acc += w1 * in[c1 * 64 + f];
    }
    if (i < e) acc += wgt[i] * in[col[i] * 64 + f];
    if (bias) acc += bias[f];
    if (relu) acc = fmaxf(acc, 0.f);
    out[node * 64 + f] = acc;
}

// ---------- dense ----------
// fused: z1 = relu(p0 @ W1 + b1) (N x 128), y2 = z1 @ W2 (N x 64), never materializing z1
__global__ void k_fuse17(const float* __restrict__ p0, const float* __restrict__ W1,
                         const float* __restrict__ b1, const float* __restrict__ W2,
                         float* __restrict__ out, int N) {
    __shared__ float pr[4][16];
    __shared__ float z1[4][128];
    int f = threadIdx.x & 63, w = threadIdx.x >> 6;
    int node = blockIdx.x * 4 + w;
    if (node < N && f < 16) pr[w][f] = p0[node * 16 + f];
    __syncthreads();
    if (node < N) {
        float a0 = b1[f], a1 = b1[f + 64];
        for (int k = 0; k < 16; ++k) {
            float p = pr[w][k];
            a0 += p * W1[k * 128 + f];
            a1 += p * W1[k * 128 + f + 64];
        }
        z1[w][f] = fmaxf(a0, 0.f);
        z1[w][f + 64] = fmaxf(a1, 0.f);
    }
    __syncthreads();
    if (node < N) {
        float a = 0.f;
        for (int k = 0; k < 128; ++k) a += z1[w][k] * W2[k * 64 + f];
        out[node * 64 + f] = a;
    }
}

// out = in @ W (+bias), 64x64 weight
__global__ void k_gemm64(const float* __restrict__ in, const float* __restrict__ W,
                         const float* __restrict__ bias, float* __restrict__ out, int N) {
    __shared__ float row[4][64];
    int f = threadIdx.x & 63, w = threadIdx.x >> 6;
    int node = blockIdx.x * 4 + w;
    if (node < N) row[w][f] = in[node * 64 + f];
    __syncthreads();
    if (node < N) {
        float a = bias ? bias[f] : 0.f;
        for (int k = 0; k < 64; ++k) a += row[w][k] * W[k * 64 + f];
        out[node * 64 + f] = a;
    }
}

// ---------- pooling + head ----------
__global__ void k_pool_init(unsigned* __restrict__ gmax) {
    gmax[blockIdx.x * 64 + threadIdx.x] = fmap(-INFINITY);
}

__global__ void k_pool(const float* __restrict__ z, const int* __restrict__ batch,
                       unsigned* __restrict__ gmax, int N) {
    int f = threadIdx.x & 63, g = threadIdx.x >> 6;
    int base = blockIdx.x * 1024;
    int curb = -1;
    float lmax = -INFINITY;
    for (int nn = g; nn < 1024; nn += 4) {
        int node = base + nn;
        if (node >= N) break;
        int b = batch[node];
        if (b != curb) {
            if (curb >= 0) atomicMax(&gmax[curb * 64 + f], fmap(lmax));
            curb = b;
            lmax = -INFINITY;
        }
        lmax = fmaxf(lmax, z[node * 64 + f]);
    }
    if (curb >= 0) atomicMax(&gmax[curb * 64 + f], fmap(lmax));
}

__global__ void k_head(const unsigned* __restrict__ gmax,
                       const float* __restrict__ Wf1, const float* __restrict__ bf1,
                       const float* __restrict__ Wf2, const float* __restrict__ bf2,
                       const float* __restrict__ Wc, const float* __restrict__ bc,
                       const float* __restrict__ Wcb, const float* __restrict__ bcb,
                       float* __restrict__ out) {
    __shared__ float g[8][64], h1[8][32], h2[8][16];
    int t = threadIdx.x;  // 64 threads
    for (int i = t; i < 512; i += 64) g[i >> 6][i & 63] = funmap(gmax[i]);
    __syncthreads();
    for (int i = t; i < 256; i += 64) {
        int r = i >> 5, c = i & 31;
        float a = bf1[c];
        for (int k = 0; k < 64; ++k) a += g[r][k] * Wf1[k * 32 + c];
        h1[r][c] = fmaxf(a, 0.f);
    }
    __syncthreads();
    for (int i = t; i < 128; i += 64) {
        int r = i >> 4, c = i & 15;
        float a = bf2[c];
        for (int k = 0; k < 32; ++k) a += h1[r][k] * Wf2[k * 16 + c];
        h2[r][c] = fmaxf(a, 0.f);
    }
    __syncthreads();
    if (t < 16) {
        int r = t & 7;
        bool comb = t >= 8;
        const float* W = comb ? Wcb : Wc;
        float a = comb ? bcb[0] : bc[0];
        for (int k = 0; k < 16; ++k) a += h2[r][k] * W[k];
        out[(comb ? 8 : 0) + r] = a;
    }
}

// ---------- launch ----------
extern "C" void kernel_launch(void* const* d_in, const int* in_sizes, int n_in,
                              void* d_out, int out_size, void* d_ws, size_t ws_size,
                              hipStream_t stream) {
    const float* x    = (const float*)d_in[0];
    const int*   ei   = (const int*)d_in[1];
    const int*   batch= (const int*)d_in[2];
    const float* W1   = (const float*)d_in[3];
    const float* b1   = (const float*)d_in[4];
    const float* W2   = (const float*)d_in[5];
    const float* b2   = (const float*)d_in[6];
    const float* Wg1  = (const float*)d_in[7];
    const float* bg1  = (const float*)d_in[8];
    const float* Wg2  = (const float*)d_in[9];
    const float* bg2  = (const float*)d_in[10];
    const float* Wg3  = (const float*)d_in[11];
    const float* bg3  = (const float*)d_in[12];
    const float* Wsg  = (const float*)d_in[13];
    const float* bsg  = (const float*)d_in[14];
    const float* Wf1  = (const float*)d_in[15];
    const float* bf1  = (const float*)d_in[16];
    const float* Wf2  = (const float*)d_in[17];
    const float* bf2  = (const float*)d_in[18];
    const float* Wc   = (const float*)d_in[19];
    const float* bc   = (const float*)d_in[20];
    const float* Wcb  = (const float*)d_in[21];
    const float* bcb  = (const float*)d_in[22];

    const int N = in_sizes[0] / 16;
    const int E = in_sizes[1] / 2;
    const int* esrc = ei;
    const int* edst = ei + E;

    // carve workspace (256B aligned)
    char* ws = (char*)d_ws;
    auto alloc = [&](size_t bytes) -> char* {
        char* p = ws;
        ws += (bytes + 255) & ~(size_t)255;
        return p;
    };
    int*      deg   = (int*)alloc((size_t)N * 4);
    int*      cnt   = (int*)alloc((size_t)N * 4);
    int*      rowst = (int*)alloc((size_t)(N + 1) * 4);
    int*      bsum  = (int*)alloc(4096);
    float*    dis   = (float*)alloc((size_t)N * 4);
    int*      col   = (int*)alloc((size_t)E * 4);
    float*    wgt   = (float*)alloc((size_t)E * 4);
    float*    bufP  = (float*)alloc((size_t)N * 16 * 4);
    float*    bufA  = (float*)alloc((size_t)N * 64 * 4);
    float*    bufB  = (float*)alloc((size_t)N * 64 * 4);
    unsigned* gmax  = (unsigned*)alloc((size_t)G_GRAPHS * 64 * 4);

    hipMemsetAsync(deg, 0, (size_t)N * 4, stream);
    hipMemsetAsync(cnt, 0, (size_t)N * 4, stream);

    const int EB = (E + 255) / 256;
    const int NB = (N + 255) / 256;
    const int NW = (N + 3) / 4;  // wave-per-node grids

    k_count<<<EB, 256, 0, stream>>>(edst, deg, E);
    k_dis<<<NB, 256, 0, stream>>>(deg, dis, N);
    k_scanA<<<NB, 256, 0, stream>>>(deg, rowst, bsum, N);
    k_scanB<<<1, 512, 0, stream>>>(bsum, NB);
    k_scanC<<<NB, 256, 0, stream>>>(rowst, bsum, N);
    k_fill<<<EB, 256, 0, stream>>>(esrc, edst, dis, rowst, cnt, col, wgt, E);

    // encoder: p0 = prop(x); z1 = relu(p0@W1+b1); y2 = z1@W2; z2 = prop(y2)+b2
    k_prop16<<<(N + 15) / 16, 256, 0, stream>>>(x, bufP, dis, rowst, deg, col, wgt, N);
    k_fuse17<<<NW, 256, 0, stream>>>(bufP, W1, b1, W2, bufA, N);
    k_prop64<<<NW, 256, 0, stream>>>(bufA, bufB, dis, rowst, deg, col, wgt, b2, 0, N);

    // stacked GCNs: z = relu(prop(z@Wg)+bg)
    k_gemm64<<<NW, 256, 0, stream>>>(bufB, Wg1, nullptr, bufA, N);
    k_prop64<<<NW, 256, 0, stream>>>(bufA, bufB, dis, rowst, deg, col, wgt, bg1, 1, N);
    k_gemm64<<<NW, 256, 0, stream>>>(bufB, Wg2, nullptr, bufA, N);
    k_prop64<<<NW, 256, 0, stream>>>(bufA, bufB, dis, rowst, deg, col, wgt, bg2, 1, N);
    k_gemm64<<<NW, 256, 0, stream>>>(bufB, Wg3, nullptr, bufA, N);
    k_prop64<<<NW, 256, 0, stream>>>(bufA, bufB, dis, rowst, deg, col, wgt, bg3, 1, N);

    // SGConv: 4 props then @Wsg + bsg
    k_prop64<<<NW, 256, 0, stream>>>(bufB, bufA, dis, rowst, deg, col, wgt, nullptr, 0, N);
    k_prop64<<<NW, 256, 0, stream>>>(bufA, bufB, dis, rowst, deg, col, wgt, nullptr, 0, N);
    k_prop64<<<NW, 256, 0, stream>>>(bufB, bufA, dis, rowst, deg, col, wgt, nullptr, 0, N);
    k_prop64<<<NW, 256, 0, stream>>>(bufA, bufB, dis, rowst, deg, col, wgt, nullptr, 0, N);
    k_gemm64<<<NW, 256, 0, stream>>>(bufB, Wsg, bsg, bufA, N);

    // pool + head
    k_pool_init<<<G_GRAPHS, 64, 0, stream>>>(gmax);
    k_pool<<<(N + 1023) / 1024, 256, 0, stream>>>(bufA, batch, gmax, N);
    k_head<<<1, 64, 0, stream>>>(gmax, Wf1, bf1, Wf2, bf2, Wc, bc, Wcb, bcb, (float*)d_out);
}

// Round 2
// 862.830 us; speedup vs baseline: 1.4343x; 1.4343x over previous
//
#include <hip/hip_runtime.h>
#include <hip/hip_bf16.h>
#include <math.h>

#define G_GRAPHS 8

// ---------- helpers ----------
__device__ __forceinline__ unsigned fmap(float f) {
    unsigned b = __float_as_uint(f);
    return (b & 0x80000000u) ? ~b : (b | 0x80000000u);
}
__device__ __forceinline__ float funmap(unsigned u) {
    unsigned b = (u & 0x80000000u) ? (u & 0x7fffffffu) : ~u;
    return __uint_as_float(b);
}

// ---------- CSR build ----------
__global__ void k_count(const int* __restrict__ dst, int* __restrict__ deg, int E) {
    int e = blockIdx.x * 256 + threadIdx.x;
    if (e < E) atomicAdd(&deg[dst[e]], 1);
}

__global__ void k_dis(const int* __restrict__ deg, float* __restrict__ dis, int N) {
    int i = blockIdx.x * 256 + threadIdx.x;
    if (i < N) dis[i] = rsqrtf((float)(deg[i] + 1));  // +1 = self loop
}

__global__ void k_scanA(const int* __restrict__ deg, int* __restrict__ rowst,
                        int* __restrict__ bsum, int N) {
    __shared__ int s[256];
    int i = blockIdx.x * 256 + threadIdx.x;
    int v = (i < N) ? deg[i] : 0;
    s[threadIdx.x] = v;
    __syncthreads();
    for (int off = 1; off < 256; off <<= 1) {
        int t = (threadIdx.x >= off) ? s[threadIdx.x - off] : 0;
        __syncthreads();
        s[threadIdx.x] += t;
        __syncthreads();
    }
    if (i < N) rowst[i] = s[threadIdx.x] - v;   // block-local exclusive
    if (threadIdx.x == 255) bsum[blockIdx.x] = s[255];
}

__global__ void k_scanB(int* __restrict__ bsum, int NB) {
    __shared__ int s[512];
    int t = threadIdx.x;
    int v = (t < NB) ? bsum[t] : 0;
    s[t] = v;
    __syncthreads();
    for (int off = 1; off < 512; off <<= 1) {
        int x = (t >= off) ? s[t - off] : 0;
        __syncthreads();
        s[t] += x;
        __syncthreads();
    }
    if (t < NB) bsum[t] = s[t] - v;             // exclusive
}

__global__ void k_scanC(int* __restrict__ rowst, const int* __restrict__ bsum, int N) {
    int i = blockIdx.x * 256 + threadIdx.x;
    if (i < N) rowst[i] += bsum[blockIdx.x];
}

__global__ void k_fill(const int* __restrict__ src, const int* __restrict__ dst,
                       const float* __restrict__ dis, const int* __restrict__ rowst,
                       int* __restrict__ cnt, int* __restrict__ col,
                       float* __restrict__ wgt, int E) {
    int e = blockIdx.x * 256 + threadIdx.x;
    if (e >= E) return;
    int d = dst[e], s = src[e];
    int p = rowst[d] + atomicAdd(&cnt[d], 1);
    col[p] = s;
    wgt[p] = dis[s] * dis[d];
}

// ---------- encoder: out = relu(prop(x)@W1+b1)@W2  (wave per node) ----------
__global__ __launch_bounds__(256) void k_enc(
        const float* __restrict__ x, float* __restrict__ out,
        const float* __restrict__ dis, const int* __restrict__ rowst,
        const int* __restrict__ deg, const int* __restrict__ col,
        const float* __restrict__ wgt,
        const float* __restrict__ W1, const float* __restrict__ b1,
        const float* __restrict__ W2, int N) {
    __shared__ float prow[4][16];
    __shared__ float z1buf[4][128];
    int t = threadIdx.x, lane = t & 63, w = t >> 6;
    int qq = lane & 3, e = lane >> 2;          // 16 edge groups x 4 lanes (float4)
    int node = blockIdx.x * 4 + w;
    if (node >= N) return;
    const float4* x4 = (const float4*)x;
    float d = dis[node];
    float sc = d * d * (1.f / 16.f);           // self-loop spread over 16 groups
    float4 sf = x4[node * 4 + qq];
    float ax = sf.x * sc, ay = sf.y * sc, az = sf.z * sc, aw = sf.w * sc;
    int s = rowst[node], dg = deg[node];
    for (int i = e; i < dg; i += 16) {
        int c = col[s + i];
        float wv = wgt[s + i];
        float4 r = x4[c * 4 + qq];
        ax += wv * r.x; ay += wv * r.y; az += wv * r.z; aw += wv * r.w;
    }
    // reduce 16 edge-groups (lanes with same qq): xor 4,8,16,32
    ax += __shfl_xor(ax, 4);  ay += __shfl_xor(ay, 4);  az += __shfl_xor(az, 4);  aw += __shfl_xor(aw, 4);
    ax += __shfl_xor(ax, 8);  ay += __shfl_xor(ay, 8);  az += __shfl_xor(az, 8);  aw += __shfl_xor(aw, 8);
    ax += __shfl_xor(ax, 16); ay += __shfl_xor(ay, 16); az += __shfl_xor(az, 16); aw += __shfl_xor(aw, 16);
    ax += __shfl_xor(ax, 32); ay += __shfl_xor(ay, 32); az += __shfl_xor(az, 32); aw += __shfl_xor(aw, 32);
    if (lane < 4)
        ((float4*)prow[w])[lane] = make_float4(ax, ay, az, aw);
    // z1 = relu(p@W1+b1): each lane produces features lane, lane+64
    float a0 = b1[lane], a1 = b1[lane + 64];
    for (int k = 0; k < 16; ++k) {
        float p = prow[w][k];
        a0 += p * W1[k * 128 + lane];
        a1 += p * W1[k * 128 + lane + 64];
    }
    z1buf[w][lane] = fmaxf(a0, 0.f);
    z1buf[w][lane + 64] = fmaxf(a1, 0.f);
    // y2 = z1@W2
    float a = 0.f;
    for (int k = 0; k < 128; ++k)
        a += z1buf[w][k] * W2[k * 64 + lane];
    out[node * 64 + lane] = a;
}

// ---------- prop64: z = prop(in)+bias [relu]; out = W ? z@W (+gbias) : z ----------
__global__ __launch_bounds__(256) void k_prop64(
        const float* __restrict__ in, float* __restrict__ out,
        const float* __restrict__ dis, const int* __restrict__ rowst,
        const int* __restrict__ deg, const int* __restrict__ col,
        const float* __restrict__ wgt,
        const float* __restrict__ bias, int relu,
        const float* __restrict__ W, const float* __restrict__ gbias, int N) {
    __shared__ float rowbuf[4][64];
    int t = threadIdx.x, lane = t & 63, w = t >> 6;
    int q = lane & 15, g = lane >> 4;          // 4 edge groups x 16 lanes (float4)
    int node = blockIdx.x * 4 + w;
    if (node >= N) return;
    const float4* in4 = (const float4*)in;
    float d = dis[node];
    float sc = d * d * 0.25f;                  // self-loop spread over 4 groups
    float4 sf = in4[node * 16 + q];
    float ax = sf.x * sc, ay = sf.y * sc, az = sf.z * sc, aw = sf.w * sc;
    int s = rowst[node], dg = deg[node];
    for (int i = g; i < dg; i += 4) {
        int c = col[s + i];
        float wv = wgt[s + i];
        float4 r = in4[c * 16 + q];
        ax += wv * r.x; ay += wv * r.y; az += wv * r.z; aw += wv * r.w;
    }
    // reduce 4 edge-groups: xor 16, 32
    ax += __shfl_xor(ax, 16); ay += __shfl_xor(ay, 16); az += __shfl_xor(az, 16); aw += __shfl_xor(aw, 16);
    ax += __shfl_xor(ax, 32); ay += __shfl_xor(ay, 32); az += __shfl_xor(az, 32); aw += __shfl_xor(aw, 32);
    if (bias) {
        float4 b4 = ((const float4*)bias)[q];
        ax += b4.x; ay += b4.y; az += b4.z; aw += b4.w;
    }
    if (relu) {
        ax = fmaxf(ax, 0.f); ay = fmaxf(ay, 0.f); az = fmaxf(az, 0.f); aw = fmaxf(aw, 0.f);
    }
    if (!W) {
        if (g == 0)
            ((float4*)out)[node * 16 + q] = make_float4(ax, ay, az, aw);
    } else {
        if (g == 0)
            ((float4*)rowbuf[w])[q] = make_float4(ax, ay, az, aw);
        float a = gbias ? gbias[lane] : 0.f;
        for (int k = 0; k < 64; ++k)
            a += rowbuf[w][k] * W[k * 64 + lane];
        out[node * 64 + lane] = a;
    }
}

// ---------- pooling + head ----------
__global__ void k_pool_init(unsigned* __restrict__ gmax) {
    gmax[blockIdx.x * 64 + threadIdx.x] = fmap(-INFINITY);
}

__global__ void k_pool(const float* __restrict__ z, const int* __restrict__ batch,
                       unsigned* __restrict__ gmax, int N) {
    int f = threadIdx.x & 63, w = threadIdx.x >> 6;
    int base = (blockIdx.x * 4 + w) * 32;
    if (base >= N) return;
    int end = base + 32; if (end > N) end = N;
    int b0 = batch[base], b1 = batch[end - 1];
    if (b0 == b1) {                            // fast path: single graph in window
        float lmax = -INFINITY;
        for (int n = base; n < end; ++n)
            lmax = fmaxf(lmax, z[n * 64 + f]);
        atomicMax(&gmax[b0 * 64 + f], fmap(lmax));
    } else {
        int curb = b0; float lmax = -INFINITY;
        for (int n = base; n < end; ++n) {
            int b = batch[n];
            if (b != curb) {
                atomicMax(&gmax[curb * 64 + f], fmap(lmax));
                curb = b; lmax = -INFINITY;
            }
            lmax = fmaxf(lmax, z[n * 64 + f]);
        }
        atomicMax(&gmax[curb * 64 + f], fmap(lmax));
    }
}

__global__ void k_head(const unsigned* __restrict__ gmax,
                       const float* __restrict__ Wf1, const float* __restrict__ bf1,
                       const float* __restrict__ Wf2, const float* __restrict__ bf2,
                       const float* __restrict__ Wc, const float* __restrict__ bc,
                       const float* __restrict__ Wcb, const float* __restrict__ bcb,
                       float* __restrict__ out) {
    __shared__ float g[8][64], h1[8][32], h2[8][16];
    int t = threadIdx.x;  // 64 threads
    for (int i = t; i < 512; i += 64) g[i >> 6][i & 63] = funmap(gmax[i]);
    __syncthreads();
    for (int i = t; i < 256; i += 64) {
        int r = i >> 5, c = i & 31;
        float a = bf1[c];
        for (int k = 0; k < 64; ++k) a += g[r][k] * Wf1[k * 32 + c];
        h1[r][c] = fmaxf(a, 0.f);
    }
    __syncthreads();
    for (int i = t; i < 128; i += 64) {
        int r = i >> 4, c = i & 15;
        float a = bf2[c];
        for (int k = 0; k < 32; ++k) a += h1[r][k] * Wf2[k * 16 + c];
        h2[r][c] = fmaxf(a, 0.f);
    }
    __syncthreads();
    if (t < 16) {
        int r = t & 7;
        bool comb = t >= 8;
        const float* W = comb ? Wcb : Wc;
        float a = comb ? bcb[0] : bc[0];
        for (int k = 0; k < 16; ++k) a += h2[r][k] * W[k];
        out[(comb ? 8 : 0) + r] = a;
    }
}

// ---------- launch ----------
extern "C" void kernel_launch(void* const* d_in, const int* in_sizes, int n_in,
                              void* d_out, int out_size, void* d_ws, size_t ws_size,
                              hipStream_t stream) {
    const float* x    = (const float*)d_in[0];
    const int*   ei   = (const int*)d_in[1];
    const int*   batch= (const int*)d_in[2];
    const float* W1   = (const float*)d_in[3];
    const float* b1   = (const float*)d_in[4];
    const float* W2   = (const float*)d_in[5];
    const float* b2   = (const float*)d_in[6];
    const float* Wg1  = (const float*)d_in[7];
    const float* bg1  = (const float*)d_in[8];
    const float* Wg2  = (const float*)d_in[9];
    const float* bg2  = (const float*)d_in[10];
    const float* Wg3  = (const float*)d_in[11];
    const float* bg3  = (const float*)d_in[12];
    const float* Wsg  = (const float*)d_in[13];
    const float* bsg  = (const float*)d_in[14];
    const float* Wf1  = (const float*)d_in[15];
    const float* bf1  = (const float*)d_in[16];
    const float* Wf2  = (const float*)d_in[17];
    const float* bf2  = (const float*)d_in[18];
    const float* Wc   = (const float*)d_in[19];
    const float* bc   = (const float*)d_in[20];
    const float* Wcb  = (const float*)d_in[21];
    const float* bcb  = (const float*)d_in[22];

    const int N = in_sizes[0] / 16;
    const int E = in_sizes[1] / 2;
    const int* esrc = ei;
    const int* edst = ei + E;

    char* ws = (char*)d_ws;
    auto alloc = [&](size_t bytes) -> char* {
        char* p = ws;
        ws += (bytes + 255) & ~(size_t)255;
        return p;
    };
    int*      deg   = (int*)alloc((size_t)N * 4);
    int*      cnt   = (int*)alloc((size_t)N * 4);
    int*      rowst = (int*)alloc((size_t)(N + 1) * 4);
    int*      bsum  = (int*)alloc(4096);
    float*    dis   = (float*)alloc((size_t)N * 4);
    int*      col   = (int*)alloc((size_t)E * 4);
    float*    wgt   = (float*)alloc((size_t)E * 4);
    float*    bufA  = (float*)alloc((size_t)N * 64 * 4);
    float*    bufB  = (float*)alloc((size_t)N * 64 * 4);
    unsigned* gmax  = (unsigned*)alloc((size_t)G_GRAPHS * 64 * 4);

    hipMemsetAsync(deg, 0, (size_t)N * 4, stream);
    hipMemsetAsync(cnt, 0, (size_t)N * 4, stream);

    const int EB = (E + 255) / 256;
    const int NB = (N + 255) / 256;
    const int NW = (N + 3) / 4;   // wave-per-node grids

    k_count<<<EB, 256, 0, stream>>>(edst, deg, E);
    k_dis<<<NB, 256, 0, stream>>>(deg, dis, N);
    k_scanA<<<NB, 256, 0, stream>>>(deg, rowst, bsum, N);
    k_scanB<<<1, 512, 0, stream>>>(bsum, NB);
    k_scanC<<<NB, 256, 0, stream>>>(rowst, bsum, N);
    k_fill<<<EB, 256, 0, stream>>>(esrc, edst, dis, rowst, cnt, col, wgt, E);

    // encoder: y2 = relu(prop(x)@W1+b1)@W2
    k_enc<<<NW, 256, 0, stream>>>(x, bufA, dis, rowst, deg, col, wgt, W1, b1, W2, N);
    // z2 = prop(y2)+b2; out = z2@Wg1
    k_prop64<<<NW, 256, 0, stream>>>(bufA, bufB, dis, rowst, deg, col, wgt, b2, 0, Wg1, nullptr, N);
    // z3 = relu(prop(.)+bg1); out = z3@Wg2
    k_prop64<<<NW, 256, 0, stream>>>(bufB, bufA, dis, rowst, deg, col, wgt, bg1, 1, Wg2, nullptr, N);
    // z4 = relu(prop(.)+bg2); out = z4@Wg3
    k_prop64<<<NW, 256, 0, stream>>>(bufA, bufB, dis, rowst, deg, col, wgt, bg2, 1, Wg3, nullptr, N);
    // z5 = relu(prop(.)+bg3)
    k_prop64<<<NW, 256, 0, stream>>>(bufB, bufA, dis, rowst, deg, col, wgt, bg3, 1, nullptr, nullptr, N);
    // SGConv: 3 plain props, then prop + @Wsg + bsg
    k_prop64<<<NW, 256, 0, stream>>>(bufA, bufB, dis, rowst, deg, col, wgt, nullptr, 0, nullptr, nullptr, N);
    k_prop64<<<NW, 256, 0, stream>>>(bufB, bufA, dis, rowst, deg, col, wgt, nullptr, 0, nullptr, nullptr, N);
    k_prop64<<<NW, 256, 0, stream>>>(bufA, bufB, dis, rowst, deg, col, wgt, nullptr, 0, nullptr, nullptr, N);
    k_prop64<<<NW, 256, 0, stream>>>(bufB, bufA, dis, rowst, deg, col, wgt, nullptr, 0, Wsg, bsg, N);

    // pool + head
    k_pool_init<<<G_GRAPHS, 64, 0, stream>>>(gmax);
    k_pool<<<(N + 127) / 128, 256, 0, stream>>>(bufA, batch, gmax, N);
    k_head<<<1, 64, 0, stream>>>(gmax, Wf1, bf1, Wf2, bf2, Wc, bc, Wcb, bcb, (float*)d_out);
}